// Round 1
// baseline (297.941 us; speedup 1.0000x reference)
//
#include <hip/hip_runtime.h>
#include <hip/hip_bf16.h>

typedef __attribute__((ext_vector_type(8))) short short8;
typedef __attribute__((ext_vector_type(4))) float f32x4;

static constexpr int Cdim = 2048;
static constexpr int NFRM = 512;        // B*T
static constexpr int Pdim = 16;
static constexpr int MROWS = NFRM * Pdim;   // 8192
static constexpr float EPS = 1e-5f;

// round-to-nearest-even fp32 -> bf16 bits
__device__ __forceinline__ unsigned short f2b(float x) {
  union { float f; unsigned u; } v; v.f = x;
  unsigned r = v.u + 0x7fffu + ((v.u >> 16) & 1u);
  return (unsigned short)(r >> 16);
}

__device__ __forceinline__ void gload16(const void* g, void* l) {
  __builtin_amdgcn_global_load_lds(
      (const __attribute__((address_space(1))) unsigned int*)g,
      (__attribute__((address_space(3))) unsigned int*)l, 16, 0, 0);
}

// cast three 2048x2048 fp32 weights to bf16
__global__ __launch_bounds__(256) void cast3_kernel(
    const float* __restrict__ s0, const float* __restrict__ s1, const float* __restrict__ s2,
    unsigned short* __restrict__ d0, unsigned short* __restrict__ d1, unsigned short* __restrict__ d2)
{
  long i = (long)blockIdx.x * 256 + threadIdx.x;   // float4 index, 3 * 1048576 total
  const float* s; unsigned short* d; long off;
  if (i < 1048576)      { s = s0; d = d0; off = i; }
  else if (i < 2097152) { s = s1; d = d1; off = i - 1048576; }
  else                  { s = s2; d = d2; off = i - 2097152; }
  float4 v = reinterpret_cast<const float4*>(s)[off];
  union { unsigned short u[4]; unsigned long long q; } o;
  o.u[0] = f2b(v.x); o.u[1] = f2b(v.y); o.u[2] = f2b(v.z); o.u[3] = f2b(v.w);
  *reinterpret_cast<unsigned long long*>(d + off * 4) = o.q;
}

// mean over P (16 rows) per frame, cast to bf16: Mb[512,2048]
__global__ __launch_bounds__(256) void mean_cast_kernel(
    const float* __restrict__ X, unsigned short* __restrict__ Mb)
{
  int idx = blockIdx.x * 256 + threadIdx.x;    // (n, c4): 512 * 512
  int n  = idx >> 9;
  int c4 = idx & 511;
  const float4* xp = reinterpret_cast<const float4*>(X) + (long)n * (Pdim * 512) + c4;
  float4 s = {0.f, 0.f, 0.f, 0.f};
  #pragma unroll
  for (int p = 0; p < Pdim; ++p) {
    float4 v = xp[(long)p * 512];
    s.x += v.x; s.y += v.y; s.z += v.z; s.w += v.w;
  }
  const float r = 1.f / 16.f;
  union { unsigned short u[4]; unsigned long long q; } o;
  o.u[0] = f2b(s.x * r); o.u[1] = f2b(s.y * r); o.u[2] = f2b(s.z * r); o.u[3] = f2b(s.w * r);
  *reinterpret_cast<unsigned long long*>(Mb + (long)idx * 4) = o.q;
}

// Xg[np, c] = bf16(X[np, c] * attn[n, c])
__global__ __launch_bounds__(256) void gate_kernel(
    const float* __restrict__ X, const float* __restrict__ attn, unsigned short* __restrict__ Xg)
{
  long idx = (long)blockIdx.x * 256 + threadIdx.x;   // float4 idx over 8192*512
  int c4 = (int)(idx & 511);
  long np = idx >> 9;
  long n  = np >> 4;
  float4 x = reinterpret_cast<const float4*>(X)[idx];
  float4 a = reinterpret_cast<const float4*>(attn)[n * 512 + c4];
  union { unsigned short u[4]; unsigned long long q; } o;
  o.u[0] = f2b(x.x * a.x); o.u[1] = f2b(x.y * a.y);
  o.u[2] = f2b(x.z * a.z); o.u[3] = f2b(x.w * a.w);
  *reinterpret_cast<unsigned long long*>(Xg + idx * 4) = o.q;
}

// C[M,N] = A[M,K] @ B[N,K]^T  (bf16 in, fp32 accum), epilogues:
//   EPI=0: Cf = sigmoid(acc + bias)          (fp32 out)
//   EPI=1: Cb = bf16(relu(BN_P16(acc)*gamma+beta))   (bias cancels in BN)
//   EPI=2: Cf = acc + bias                   (fp32 out)
template<int EPI>
__global__ __launch_bounds__(256) void gemm_bt(
    const unsigned short* __restrict__ A,
    const unsigned short* __restrict__ B,
    int M, int N, int K,
    const float* __restrict__ bias,
    const float* __restrict__ gamma,
    const float* __restrict__ beta,
    float* __restrict__ Cf,
    unsigned short* __restrict__ Cb)
{
  __shared__ unsigned short As[128 * 32];
  __shared__ unsigned short Bs[128 * 32];
  const int t = threadIdx.x;
  const int lane = t & 63;
  const int wid = t >> 6;
  const int wr = wid >> 1, wc = wid & 1;
  const int m0 = blockIdx.x * 128, n0 = blockIdx.y * 128;

  f32x4 acc[4][4];
  #pragma unroll
  for (int i = 0; i < 4; i++)
    #pragma unroll
    for (int j = 0; j < 4; j++) acc[i][j] = (f32x4){0.f, 0.f, 0.f, 0.f};

  // staging: thread t loads 8 bf16 (16B); tile row = t/4, col8 = (t%4)*8
  const int srow = t >> 2;
  const int scol = (t & 3) * 8;
  const long aoff0 = (long)(m0 + srow) * K + scol;
  const long aoff1 = (long)(m0 + 64 + srow) * K + scol;
  const long boff0 = (long)(n0 + srow) * K + scol;
  const long boff1 = (long)(n0 + 64 + srow) * K + scol;
  char* AsB = (char*)As;
  char* BsB = (char*)Bs;

  const int fr = lane & 15;
  const int fk = (lane >> 4) * 8;

  for (int kt = 0; kt < K; kt += 32) {
    __syncthreads();
    gload16(A + aoff0 + kt, AsB + t * 16);
    gload16(A + aoff1 + kt, AsB + 4096 + t * 16);
    gload16(B + boff0 + kt, BsB + t * 16);
    gload16(B + boff1 + kt, BsB + 4096 + t * 16);
    __syncthreads();
    short8 af[4], bfr[4];
    #pragma unroll
    for (int m = 0; m < 4; m++)
      af[m] = *reinterpret_cast<const short8*>(&As[(wr * 64 + m * 16 + fr) * 32 + fk]);
    #pragma unroll
    for (int n = 0; n < 4; n++)
      bfr[n] = *reinterpret_cast<const short8*>(&Bs[(wc * 64 + n * 16 + fr) * 32 + fk]);
    #pragma unroll
    for (int m = 0; m < 4; m++)
      #pragma unroll
      for (int n = 0; n < 4; n++)
        acc[m][n] = __builtin_amdgcn_mfma_f32_16x16x32_bf16(af[m], bfr[n], acc[m][n], 0, 0, 0);
  }

  const int l4 = lane >> 4;
  #pragma unroll
  for (int m = 0; m < 4; m++) {
    const int r0 = m0 + wr * 64 + m * 16 + l4 * 4;
    #pragma unroll
    for (int n = 0; n < 4; n++) {
      const int cn = n0 + wc * 64 + n * 16 + fr;
      if constexpr (EPI == 0) {
        const float bb = bias[cn];
        #pragma unroll
        for (int j = 0; j < 4; j++) {
          float v = acc[m][n][j] + bb;
          v = 1.f / (1.f + __expf(-v));
          Cf[(long)(r0 + j) * N + cn] = v;
        }
      } else if constexpr (EPI == 1) {
        // fragment m spans exactly one frame's 16 rows -> BN over P inside frag
        float s1 = 0.f, s2 = 0.f;
        #pragma unroll
        for (int j = 0; j < 4; j++) { float v = acc[m][n][j]; s1 += v; s2 += v * v; }
        s1 += __shfl_xor(s1, 16); s2 += __shfl_xor(s2, 16);
        s1 += __shfl_xor(s1, 32); s2 += __shfl_xor(s2, 32);
        const float mean = s1 * 0.0625f;
        const float var  = s2 * 0.0625f - mean * mean;
        const float sc = rsqrtf(var + EPS) * gamma[cn];
        const float sh = beta[cn] - mean * sc;
        #pragma unroll
        for (int j = 0; j < 4; j++) {
          float v = fmaxf(acc[m][n][j] * sc + sh, 0.f);
          Cb[(long)(r0 + j) * N + cn] = f2b(v);
        }
      } else {
        const float bb = bias[cn];
        #pragma unroll
        for (int j = 0; j < 4; j++)
          Cf[(long)(r0 + j) * N + cn] = acc[m][n][j] + bb;
      }
    }
  }
}

extern "C" void kernel_launch(void* const* d_in, const int* in_sizes, int n_in,
                              void* d_out, int out_size, void* d_ws, size_t ws_size,
                              hipStream_t stream) {
  const float* X     = (const float*)d_in[0];
  const float* W_att = (const float*)d_in[1];
  const float* b_att = (const float*)d_in[2];
  const float* W1    = (const float*)d_in[3];
  // d_in[4] = b1: cancels exactly in BN (mean-subtracted) -> unused
  const float* gamma = (const float*)d_in[5];
  const float* beta  = (const float*)d_in[6];
  const float* W2    = (const float*)d_in[7];
  const float* b2    = (const float*)d_in[8];
  float* out = (float*)d_out;

  char* ws = (char*)d_ws;
  unsigned short* Wab = (unsigned short*)(ws + 0);            //  8 MB
  unsigned short* W1b = (unsigned short*)(ws + 8388608);      //  8 MB
  unsigned short* W2b = (unsigned short*)(ws + 16777216);     //  8 MB
  unsigned short* Mb  = (unsigned short*)(ws + 25165824);     //  2 MB
  float*          At  = (float*)        (ws + 27262976);      //  4 MB
  unsigned short* Xg  = (unsigned short*)(ws + 31457280);     // 32 MB
  unsigned short* Hr  = (unsigned short*)(ws + 67108864);     // 32 MB  (total 96 MB)

  hipLaunchKernelGGL(cast3_kernel, dim3(12288), dim3(256), 0, stream,
                     W_att, W1, W2, Wab, W1b, W2b);
  hipLaunchKernelGGL(mean_cast_kernel, dim3(1024), dim3(256), 0, stream, X, Mb);
  hipLaunchKernelGGL((gemm_bt<0>), dim3(4, 16), dim3(256), 0, stream,
                     Mb, Wab, 512, Cdim, Cdim, b_att, nullptr, nullptr, At, nullptr);
  hipLaunchKernelGGL(gate_kernel, dim3(16384), dim3(256), 0, stream, X, At, Xg);
  hipLaunchKernelGGL((gemm_bt<1>), dim3(64, 16), dim3(256), 0, stream,
                     Xg, W1b, MROWS, Cdim, Cdim, nullptr, gamma, beta, nullptr, Hr);
  hipLaunchKernelGGL((gemm_bt<2>), dim3(64, 16), dim3(256), 0, stream,
                     Hr, W2b, MROWS, Cdim, Cdim, b2, nullptr, nullptr, out, nullptr);
}

// Round 2
// 219.719 us; speedup vs baseline: 1.3560x; 1.3560x over previous
//
#include <hip/hip_runtime.h>
#include <hip/hip_bf16.h>

typedef __attribute__((ext_vector_type(8))) short short8;
typedef __attribute__((ext_vector_type(4))) float f32x4;

static constexpr int Cdim = 2048;
static constexpr int NFRM = 512;        // B*T
static constexpr int Pdim = 16;
static constexpr int MROWS = NFRM * Pdim;   // 8192
static constexpr float EPS = 1e-5f;

// round-to-nearest-even fp32 -> bf16 bits
__device__ __forceinline__ unsigned short f2b(float x) {
  union { float f; unsigned u; } v; v.f = x;
  unsigned r = v.u + 0x7fffu + ((v.u >> 16) & 1u);
  return (unsigned short)(r >> 16);
}

__device__ __forceinline__ void gload16(const void* g, void* l) {
  __builtin_amdgcn_global_load_lds(
      (const __attribute__((address_space(1))) unsigned int*)g,
      (__attribute__((address_space(3))) unsigned int*)l, 16, 0, 0);
}

// ---------------- small prep kernels (unchanged from R1) ----------------

__global__ __launch_bounds__(256) void cast3_kernel(
    const float* __restrict__ s0, const float* __restrict__ s1, const float* __restrict__ s2,
    unsigned short* __restrict__ d0, unsigned short* __restrict__ d1, unsigned short* __restrict__ d2)
{
  long i = (long)blockIdx.x * 256 + threadIdx.x;
  const float* s; unsigned short* d; long off;
  if (i < 1048576)      { s = s0; d = d0; off = i; }
  else if (i < 2097152) { s = s1; d = d1; off = i - 1048576; }
  else                  { s = s2; d = d2; off = i - 2097152; }
  float4 v = reinterpret_cast<const float4*>(s)[off];
  union { unsigned short u[4]; unsigned long long q; } o;
  o.u[0] = f2b(v.x); o.u[1] = f2b(v.y); o.u[2] = f2b(v.z); o.u[3] = f2b(v.w);
  *reinterpret_cast<unsigned long long*>(d + off * 4) = o.q;
}

__global__ __launch_bounds__(256) void mean_cast_kernel(
    const float* __restrict__ X, unsigned short* __restrict__ Mb)
{
  int idx = blockIdx.x * 256 + threadIdx.x;
  int n  = idx >> 9;
  int c4 = idx & 511;
  const float4* xp = reinterpret_cast<const float4*>(X) + (long)n * (Pdim * 512) + c4;
  float4 s = {0.f, 0.f, 0.f, 0.f};
  #pragma unroll
  for (int p = 0; p < Pdim; ++p) {
    float4 v = xp[(long)p * 512];
    s.x += v.x; s.y += v.y; s.z += v.z; s.w += v.w;
  }
  const float r = 1.f / 16.f;
  union { unsigned short u[4]; unsigned long long q; } o;
  o.u[0] = f2b(s.x * r); o.u[1] = f2b(s.y * r); o.u[2] = f2b(s.z * r); o.u[3] = f2b(s.w * r);
  *reinterpret_cast<unsigned long long*>(Mb + (long)idx * 4) = o.q;
}

__global__ __launch_bounds__(256) void gate_kernel(
    const float* __restrict__ X, const float* __restrict__ attn, unsigned short* __restrict__ Xg)
{
  long idx = (long)blockIdx.x * 256 + threadIdx.x;
  int c4 = (int)(idx & 511);
  long np = idx >> 9;
  long n  = np >> 4;
  float4 x = reinterpret_cast<const float4*>(X)[idx];
  float4 a = reinterpret_cast<const float4*>(attn)[n * 512 + c4];
  union { unsigned short u[4]; unsigned long long q; } o;
  o.u[0] = f2b(x.x * a.x); o.u[1] = f2b(x.y * a.y);
  o.u[2] = f2b(x.z * a.z); o.u[3] = f2b(x.w * a.w);
  *reinterpret_cast<unsigned long long*>(Xg + idx * 4) = o.q;
}

// ---------------- 128^2 m97-structure GEMM, kept for the small attn GEMM ----------------
// EPI=0: Cf = sigmoid(acc + bias)
__global__ __launch_bounds__(256) void gemm_att(
    const unsigned short* __restrict__ A,
    const unsigned short* __restrict__ B,
    int M, int N, int K,
    const float* __restrict__ bias,
    float* __restrict__ Cf)
{
  __shared__ unsigned short As[128 * 32];
  __shared__ unsigned short Bs[128 * 32];
  const int t = threadIdx.x;
  const int lane = t & 63;
  const int wid = t >> 6;
  const int wr = wid >> 1, wc = wid & 1;
  const int m0 = blockIdx.x * 128, n0 = blockIdx.y * 128;

  f32x4 acc[4][4];
  #pragma unroll
  for (int i = 0; i < 4; i++)
    #pragma unroll
    for (int j = 0; j < 4; j++) acc[i][j] = (f32x4){0.f, 0.f, 0.f, 0.f};

  const int srow = t >> 2;
  const int scol = (t & 3) * 8;
  const long aoff0 = (long)(m0 + srow) * K + scol;
  const long aoff1 = (long)(m0 + 64 + srow) * K + scol;
  const long boff0 = (long)(n0 + srow) * K + scol;
  const long boff1 = (long)(n0 + 64 + srow) * K + scol;
  char* AsB = (char*)As;
  char* BsB = (char*)Bs;

  const int fr = lane & 15;
  const int fk = (lane >> 4) * 8;

  for (int kt = 0; kt < K; kt += 32) {
    __syncthreads();
    gload16(A + aoff0 + kt, AsB + t * 16);
    gload16(A + aoff1 + kt, AsB + 4096 + t * 16);
    gload16(B + boff0 + kt, BsB + t * 16);
    gload16(B + boff1 + kt, BsB + 4096 + t * 16);
    __syncthreads();
    short8 af[4], bfr[4];
    #pragma unroll
    for (int m = 0; m < 4; m++)
      af[m] = *reinterpret_cast<const short8*>(&As[(wr * 64 + m * 16 + fr) * 32 + fk]);
    #pragma unroll
    for (int n = 0; n < 4; n++)
      bfr[n] = *reinterpret_cast<const short8*>(&Bs[(wc * 64 + n * 16 + fr) * 32 + fk]);
    #pragma unroll
    for (int m = 0; m < 4; m++)
      #pragma unroll
      for (int n = 0; n < 4; n++)
        acc[m][n] = __builtin_amdgcn_mfma_f32_16x16x32_bf16(af[m], bfr[n], acc[m][n], 0, 0, 0);
  }

  const int l4 = lane >> 4;
  #pragma unroll
  for (int m = 0; m < 4; m++) {
    const int r0 = m0 + wr * 64 + m * 16 + l4 * 4;
    #pragma unroll
    for (int n = 0; n < 4; n++) {
      const int cn = n0 + wc * 64 + n * 16 + fr;
      const float bb = bias[cn];
      #pragma unroll
      for (int j = 0; j < 4; j++) {
        float v = acc[m][n][j] + bb;
        v = 1.f / (1.f + __expf(-v));
        Cf[(long)(r0 + j) * N + cn] = v;
      }
    }
  }
}

// ---------------- 256^2 8-phase GEMM (T1+T2+T3+T4+T5) ----------------
// C[M,N] = A[M,K] @ B[N,K]^T, bf16 in / fp32 acc.
//   EPI=1: Cb = bf16(relu(BN_P16(acc)*gamma+beta))
//   EPI=2: Cf = acc + bias
// LDS: [buf:2][slot:4][16KB]; slot 0/1 = A half0/1 (rows 0-127/128-255),
//      slot 2/3 = B half0/1 (cols 0-127/128-255). Half-tile = 128 rows x 64 k x bf16.
// Swizzle (T2): LDS linear write via global_load_lds; global source col and
// LDS read col both XORed with (row&7)<<4 bytes (involution, rule 21).
// Stage schedule (deadline-derived): ph1->A0(t+1) ph2->A1(t+1) ph3->B0(t+2)
// ph4->B1(t+2); vmcnt(4) at ph4 (A-slots last read ph3, B-slots ph2).
template<int EPI>
__global__ __launch_bounds__(512, 2) void gemm256(
    const unsigned short* __restrict__ A,
    const unsigned short* __restrict__ B,
    int Kk, int Nn, int nbx,
    const float* __restrict__ bias,
    const float* __restrict__ gamma,
    const float* __restrict__ beta,
    float* __restrict__ Cf,
    unsigned short* __restrict__ Cb)
{
  __shared__ char lds[131072];
  const int t = threadIdx.x;
  const int lane = t & 63;
  const int wid = t >> 6;
  const int wr = wid >> 2;        // 0..1
  const int wc = wid & 3;         // 0..3

  // T1: bijective XCD swizzle (gridDim.x % 8 == 0 guaranteed by launch)
  const int nw = gridDim.x;
  const int wg = (blockIdx.x & 7) * (nw >> 3) + (blockIdx.x >> 3);
  const int bx = wg % nbx;
  const int by = wg / nbx;
  const int m0 = bx << 8, n0 = by << 8;

  const int NT = Kk >> 6;

  // staging per-thread invariants: loads l=t (rows 0..63) and l=t+512 (rows 64..127)
  const int row0 = t >> 3;
  const int col0 = ((t & 7) * 8) ^ ((row0 & 7) << 3);   // bf16 elements, pre-swizzled source

#define STAGE2(kt_, slot_) do { \
    const unsigned short* s_ = ((slot_) < 2) ? A : B; \
    const int br_ = (((slot_) < 2) ? m0 : n0) + (((slot_) & 1) << 7); \
    char* d_ = lds + (((kt_) & 1) << 16) + ((slot_) << 14); \
    const unsigned short* g_ = s_ + (long)(br_ + row0) * Kk + ((kt_) << 6) + col0; \
    gload16(g_, d_ + (t << 4)); \
    gload16(g_ + (long)64 * Kk, d_ + 8192 + (t << 4)); \
  } while (0)

  // fragment read offsets
  const int fr_ = lane & 15;
  const int q16 = (lane >> 4) << 4;            // 0,16,32,48
  const int cb0 = q16 ^ ((fr_ & 7) << 4);      // swizzled ks=0 byte col
  const int aBase = (wr << 14) + fr_ * 128;
  const int bBase = ((2 + (wc >> 1)) << 14) + ((wc & 1) << 13) + fr_ * 128;

#define LDA8(m_, ks_) (*(const short8*)(lds + bufo + aBase + (m_) * 2048 + (cb0 ^ ((ks_) << 6))))
#define LDB8(n_, ks_) (*(const short8*)(lds + bufo + bBase + (n_) * 2048 + (cb0 ^ ((ks_) << 6))))

#define PHASE_MID() do { \
    __builtin_amdgcn_sched_barrier(0); \
    __builtin_amdgcn_s_barrier(); \
    asm volatile("s_waitcnt lgkmcnt(0)" ::: "memory"); \
    __builtin_amdgcn_sched_barrier(0); \
    __builtin_amdgcn_s_setprio(1); \
  } while (0)
#define PHASE_END() do { \
    __builtin_amdgcn_s_setprio(0); \
    __builtin_amdgcn_sched_barrier(0); \
    __builtin_amdgcn_s_barrier(); \
    __builtin_amdgcn_sched_barrier(0); \
  } while (0)

  f32x4 acc[8][4];
  #pragma unroll
  for (int i = 0; i < 8; i++)
    #pragma unroll
    for (int j = 0; j < 4; j++) acc[i][j] = (f32x4){0.f, 0.f, 0.f, 0.f};

  short8 af[4][2], bv[4][2];

  // prologue: tile0 all 4 halves + B0(1),B1(1); leave the 2 newest in flight
  STAGE2(0, 0); STAGE2(0, 1); STAGE2(0, 2); STAGE2(0, 3);
  if (NT > 1) { STAGE2(1, 2); STAGE2(1, 3); }
  asm volatile("s_waitcnt vmcnt(4)" ::: "memory");
  __builtin_amdgcn_s_barrier();
  __builtin_amdgcn_sched_barrier(0);

  for (int kt = 0; kt < NT; ++kt) {
    const int bufo = (kt & 1) << 16;

    // ---- phase 1: (mh=0, nh=0)  reads a0-3, b0-1 (12x ds_read_b128)
    if (kt + 1 < NT) STAGE2(kt + 1, 0);
    af[0][0] = LDA8(0, 0); af[0][1] = LDA8(0, 1);
    af[1][0] = LDA8(1, 0); af[1][1] = LDA8(1, 1);
    af[2][0] = LDA8(2, 0); af[2][1] = LDA8(2, 1);
    af[3][0] = LDA8(3, 0); af[3][1] = LDA8(3, 1);
    bv[0][0] = LDB8(0, 0); bv[0][1] = LDB8(0, 1);
    bv[1][0] = LDB8(1, 0); bv[1][1] = LDB8(1, 1);
    PHASE_MID();
    #pragma unroll
    for (int mi = 0; mi < 4; ++mi)
      #pragma unroll
      for (int ni = 0; ni < 2; ++ni) {
        acc[mi][ni] = __builtin_amdgcn_mfma_f32_16x16x32_bf16(af[mi][0], bv[ni][0], acc[mi][ni], 0, 0, 0);
        acc[mi][ni] = __builtin_amdgcn_mfma_f32_16x16x32_bf16(af[mi][1], bv[ni][1], acc[mi][ni], 0, 0, 0);
      }
    PHASE_END();

    // ---- phase 2: (mh=0, nh=1)  reads b2-3
    if (kt + 1 < NT) STAGE2(kt + 1, 1);
    bv[2][0] = LDB8(2, 0); bv[2][1] = LDB8(2, 1);
    bv[3][0] = LDB8(3, 0); bv[3][1] = LDB8(3, 1);
    PHASE_MID();
    #pragma unroll
    for (int mi = 0; mi < 4; ++mi)
      #pragma unroll
      for (int ni = 0; ni < 2; ++ni) {
        acc[mi][2 + ni] = __builtin_amdgcn_mfma_f32_16x16x32_bf16(af[mi][0], bv[2 + ni][0], acc[mi][2 + ni], 0, 0, 0);
        acc[mi][2 + ni] = __builtin_amdgcn_mfma_f32_16x16x32_bf16(af[mi][1], bv[2 + ni][1], acc[mi][2 + ni], 0, 0, 0);
      }
    PHASE_END();

    // ---- phase 3: (mh=1, nh=0)  reads a4-7
    if (kt + 2 < NT) STAGE2(kt + 2, 2);
    af[0][0] = LDA8(4, 0); af[0][1] = LDA8(4, 1);
    af[1][0] = LDA8(5, 0); af[1][1] = LDA8(5, 1);
    af[2][0] = LDA8(6, 0); af[2][1] = LDA8(6, 1);
    af[3][0] = LDA8(7, 0); af[3][1] = LDA8(7, 1);
    PHASE_MID();
    #pragma unroll
    for (int mi = 0; mi < 4; ++mi)
      #pragma unroll
      for (int ni = 0; ni < 2; ++ni) {
        acc[4 + mi][ni] = __builtin_amdgcn_mfma_f32_16x16x32_bf16(af[mi][0], bv[ni][0], acc[4 + mi][ni], 0, 0, 0);
        acc[4 + mi][ni] = __builtin_amdgcn_mfma_f32_16x16x32_bf16(af[mi][1], bv[ni][1], acc[4 + mi][ni], 0, 0, 0);
      }
    PHASE_END();

    // ---- phase 4: (mh=1, nh=1)  no reads; counted vmcnt (T4)
    if (kt + 2 < NT) STAGE2(kt + 2, 3);
    if (kt < NT - 2) asm volatile("s_waitcnt vmcnt(4)" ::: "memory");
    else             asm volatile("s_waitcnt vmcnt(0)" ::: "memory");
    PHASE_MID();
    #pragma unroll
    for (int mi = 0; mi < 4; ++mi)
      #pragma unroll
      for (int ni = 0; ni < 2; ++ni) {
        acc[4 + mi][2 + ni] = __builtin_amdgcn_mfma_f32_16x16x32_bf16(af[mi][0], bv[2 + ni][0], acc[4 + mi][2 + ni], 0, 0, 0);
        acc[4 + mi][2 + ni] = __builtin_amdgcn_mfma_f32_16x16x32_bf16(af[mi][1], bv[2 + ni][1], acc[4 + mi][2 + ni], 0, 0, 0);
      }
    PHASE_END();
  }

  // ---- epilogue
  const int l4 = lane >> 4;
  #pragma unroll
  for (int m = 0; m < 8; ++m) {
    const int r0 = m0 + wr * 128 + m * 16 + l4 * 4;
    #pragma unroll
    for (int n = 0; n < 4; ++n) {
      const int cn = n0 + wc * 64 + n * 16 + fr_;
      if constexpr (EPI == 1) {
        float s1 = 0.f, s2 = 0.f;
        #pragma unroll
        for (int j = 0; j < 4; j++) { float v = acc[m][n][j]; s1 += v; s2 += v * v; }
        s1 += __shfl_xor(s1, 16); s2 += __shfl_xor(s2, 16);
        s1 += __shfl_xor(s1, 32); s2 += __shfl_xor(s2, 32);
        const float mean = s1 * 0.0625f;
        const float var  = s2 * 0.0625f - mean * mean;
        const float sc = rsqrtf(var + EPS) * gamma[cn];
        const float sh = beta[cn] - mean * sc;
        #pragma unroll
        for (int j = 0; j < 4; j++) {
          float v = fmaxf(acc[m][n][j] * sc + sh, 0.f);
          Cb[(long)(r0 + j) * Nn + cn] = f2b(v);
        }
      } else {
        const float bb = bias[cn];
        #pragma unroll
        for (int j = 0; j < 4; j++)
          Cf[(long)(r0 + j) * Nn + cn] = acc[m][n][j] + bb;
      }
    }
  }
#undef STAGE2
#undef LDA8
#undef LDB8
#undef PHASE_MID
#undef PHASE_END
}

extern "C" void kernel_launch(void* const* d_in, const int* in_sizes, int n_in,
                              void* d_out, int out_size, void* d_ws, size_t ws_size,
                              hipStream_t stream) {
  const float* X     = (const float*)d_in[0];
  const float* W_att = (const float*)d_in[1];
  const float* b_att = (const float*)d_in[2];
  const float* W1    = (const float*)d_in[3];
  // d_in[4] = b1: cancels exactly in BN (mean-subtracted) -> unused
  const float* gamma = (const float*)d_in[5];
  const float* beta  = (const float*)d_in[6];
  const float* W2    = (const float*)d_in[7];
  const float* b2    = (const float*)d_in[8];
  float* out = (float*)d_out;

  char* ws = (char*)d_ws;
  unsigned short* Wab = (unsigned short*)(ws + 0);            //  8 MB
  unsigned short* W1b = (unsigned short*)(ws + 8388608);      //  8 MB
  unsigned short* W2b = (unsigned short*)(ws + 16777216);     //  8 MB
  unsigned short* Mb  = (unsigned short*)(ws + 25165824);     //  2 MB
  float*          At  = (float*)        (ws + 27262976);      //  4 MB
  unsigned short* Xg  = (unsigned short*)(ws + 31457280);     // 32 MB
  unsigned short* Hr  = (unsigned short*)(ws + 67108864);     // 32 MB  (total 96 MB)

  hipLaunchKernelGGL(cast3_kernel, dim3(12288), dim3(256), 0, stream,
                     W_att, W1, W2, Wab, W1b, W2b);
  hipLaunchKernelGGL(mean_cast_kernel, dim3(1024), dim3(256), 0, stream, X, Mb);
  hipLaunchKernelGGL(gemm_att, dim3(4, 16), dim3(256), 0, stream,
                     Mb, Wab, 512, Cdim, Cdim, b_att, At);
  hipLaunchKernelGGL(gate_kernel, dim3(16384), dim3(256), 0, stream, X, At, Xg);
  // grid = (M/256)*(N/256) = 32*8 = 256, %8==0 -> bijective XCD swizzle
  hipLaunchKernelGGL((gemm256<1>), dim3(256), dim3(512), 0, stream,
                     Xg, W1b, Cdim, Cdim, 32, nullptr, gamma, beta, nullptr, Hr);
  hipLaunchKernelGGL((gemm256<2>), dim3(256), dim3(512), 0, stream,
                     Hr, W2b, Cdim, Cdim, 32, b2, nullptr, nullptr, out, nullptr);
}

// Round 3
// 192.869 us; speedup vs baseline: 1.5448x; 1.1392x over previous
//
#include <hip/hip_runtime.h>
#include <hip/hip_bf16.h>

typedef __attribute__((ext_vector_type(8))) short short8;
typedef __attribute__((ext_vector_type(4))) float f32x4;

static constexpr int Cdim = 2048;
static constexpr int NFRM = 512;        // B*T
static constexpr int Pdim = 16;
static constexpr int MROWS = NFRM * Pdim;   // 8192
static constexpr float EPS = 1e-5f;

// round-to-nearest-even fp32 -> bf16 bits
__device__ __forceinline__ unsigned short f2b(float x) {
  union { float f; unsigned u; } v; v.f = x;
  unsigned r = v.u + 0x7fffu + ((v.u >> 16) & 1u);
  return (unsigned short)(r >> 16);
}

__device__ __forceinline__ void gload16(const void* g, void* l) {
  __builtin_amdgcn_global_load_lds(
      (const __attribute__((address_space(1))) unsigned int*)g,
      (__attribute__((address_space(3))) unsigned int*)l, 16, 0, 0);
}

// ---------------- small prep kernels ----------------

__global__ __launch_bounds__(256) void cast3_kernel(
    const float* __restrict__ s0, const float* __restrict__ s1, const float* __restrict__ s2,
    unsigned short* __restrict__ d0, unsigned short* __restrict__ d1, unsigned short* __restrict__ d2)
{
  long i = (long)blockIdx.x * 256 + threadIdx.x;
  const float* s; unsigned short* d; long off;
  if (i < 1048576)      { s = s0; d = d0; off = i; }
  else if (i < 2097152) { s = s1; d = d1; off = i - 1048576; }
  else                  { s = s2; d = d2; off = i - 2097152; }
  float4 v = reinterpret_cast<const float4*>(s)[off];
  union { unsigned short u[4]; unsigned long long q; } o;
  o.u[0] = f2b(v.x); o.u[1] = f2b(v.y); o.u[2] = f2b(v.z); o.u[3] = f2b(v.w);
  *reinterpret_cast<unsigned long long*>(d + off * 4) = o.q;
}

__global__ __launch_bounds__(256) void mean_cast_kernel(
    const float* __restrict__ X, unsigned short* __restrict__ Mb)
{
  int idx = blockIdx.x * 256 + threadIdx.x;
  int n  = idx >> 9;
  int c4 = idx & 511;
  const float4* xp = reinterpret_cast<const float4*>(X) + (long)n * (Pdim * 512) + c4;
  float4 s = {0.f, 0.f, 0.f, 0.f};
  #pragma unroll
  for (int p = 0; p < Pdim; ++p) {
    float4 v = xp[(long)p * 512];
    s.x += v.x; s.y += v.y; s.z += v.z; s.w += v.w;
  }
  const float r = 1.f / 16.f;
  union { unsigned short u[4]; unsigned long long q; } o;
  o.u[0] = f2b(s.x * r); o.u[1] = f2b(s.y * r); o.u[2] = f2b(s.z * r); o.u[3] = f2b(s.w * r);
  *reinterpret_cast<unsigned long long*>(Mb + (long)idx * 4) = o.q;
}

// attn partials -> sigmoid gate fused here: a = sigmoid(P0+P1+b_att); Xg = bf16(X*a)
__global__ __launch_bounds__(256) void gate_kernel(
    const float* __restrict__ X, const float* __restrict__ P0, const float* __restrict__ P1,
    const float* __restrict__ b_att, unsigned short* __restrict__ Xg)
{
  long idx = (long)blockIdx.x * 256 + threadIdx.x;
  int c4 = (int)(idx & 511);
  long np = idx >> 9;
  long n  = np >> 4;
  float4 x  = reinterpret_cast<const float4*>(X)[idx];
  float4 p0 = reinterpret_cast<const float4*>(P0)[n * 512 + c4];
  float4 p1 = reinterpret_cast<const float4*>(P1)[n * 512 + c4];
  float4 bb = reinterpret_cast<const float4*>(b_att)[c4];
  float4 a;
  a.x = 1.f / (1.f + __expf(-(p0.x + p1.x + bb.x)));
  a.y = 1.f / (1.f + __expf(-(p0.y + p1.y + bb.y)));
  a.z = 1.f / (1.f + __expf(-(p0.z + p1.z + bb.z)));
  a.w = 1.f / (1.f + __expf(-(p0.w + p1.w + bb.w)));
  union { unsigned short u[4]; unsigned long long q; } o;
  o.u[0] = f2b(x.x * a.x); o.u[1] = f2b(x.y * a.y);
  o.u[2] = f2b(x.z * a.z); o.u[3] = f2b(x.w * a.w);
  *reinterpret_cast<unsigned long long*>(Xg + idx * 4) = o.q;
}

// ---------------- small attn GEMM, split-K=2, raw partial output ----------------
__global__ __launch_bounds__(256) void gemm_att_sk(
    const unsigned short* __restrict__ A,
    const unsigned short* __restrict__ B,
    float* __restrict__ P)
{
  constexpr int N = 2048, K = 2048, KH = 1024;
  __shared__ unsigned short As[128 * 32];
  __shared__ unsigned short Bs[128 * 32];
  const int t = threadIdx.x;
  const int lane = t & 63;
  const int wid = t >> 6;
  const int wr = wid >> 1, wc = wid & 1;
  const int m0 = blockIdx.x * 128, n0 = blockIdx.y * 128;
  const int k0 = blockIdx.z * KH;
  float* out = P + (long)blockIdx.z * (512L * 2048);

  f32x4 acc[4][4];
  #pragma unroll
  for (int i = 0; i < 4; i++)
    #pragma unroll
    for (int j = 0; j < 4; j++) acc[i][j] = (f32x4){0.f, 0.f, 0.f, 0.f};

  const int srow = t >> 2;
  const int scol = (t & 3) * 8;
  const long aoff0 = (long)(m0 + srow) * K + scol;
  const long aoff1 = (long)(m0 + 64 + srow) * K + scol;
  const long boff0 = (long)(n0 + srow) * K + scol;
  const long boff1 = (long)(n0 + 64 + srow) * K + scol;
  char* AsB = (char*)As;
  char* BsB = (char*)Bs;

  const int fr = lane & 15;
  const int fk = (lane >> 4) * 8;

  for (int kt = k0; kt < k0 + KH; kt += 32) {
    __syncthreads();
    gload16(A + aoff0 + kt, AsB + t * 16);
    gload16(A + aoff1 + kt, AsB + 4096 + t * 16);
    gload16(B + boff0 + kt, BsB + t * 16);
    gload16(B + boff1 + kt, BsB + 4096 + t * 16);
    __syncthreads();
    short8 af[4], bfr[4];
    #pragma unroll
    for (int m = 0; m < 4; m++)
      af[m] = *reinterpret_cast<const short8*>(&As[(wr * 64 + m * 16 + fr) * 32 + fk]);
    #pragma unroll
    for (int n = 0; n < 4; n++)
      bfr[n] = *reinterpret_cast<const short8*>(&Bs[(wc * 64 + n * 16 + fr) * 32 + fk]);
    #pragma unroll
    for (int m = 0; m < 4; m++)
      #pragma unroll
      for (int n = 0; n < 4; n++)
        acc[m][n] = __builtin_amdgcn_mfma_f32_16x16x32_bf16(af[m], bfr[n], acc[m][n], 0, 0, 0);
  }

  const int l4 = lane >> 4;
  #pragma unroll
  for (int m = 0; m < 4; m++) {
    const int r0 = m0 + wr * 64 + m * 16 + l4 * 4;
    #pragma unroll
    for (int n = 0; n < 4; n++) {
      const int cn = n0 + wc * 64 + n * 16 + fr;
      #pragma unroll
      for (int j = 0; j < 4; j++)
        out[(long)(r0 + j) * N + cn] = acc[m][n][j];
    }
  }
}

// ---------------- 256^2 balanced 8-phase GEMM (T1+T2+T3+T4+T5) ----------------
// C[M,N] = A[M,K] @ B[N,K]^T, bf16 in / fp32 acc.
//   EPI=1: Cb = bf16(relu(BN_P16(acc)*gamma+beta))
//   EPI=2: Cf = acc + bias
// LDS: [buf:2][A0,A1,B0,B1][16KB]. K unrolled x2: tile e->buf0 (P1-4), o->buf1 (P5-8).
// Reads balanced 8/4/8/4 per phase (b0-fragments read one phase early: P4/P8).
// Stage schedule: P1:A0(o) P2:A1(o) P3:B0(e+2) P4:B1(e+2) P5:A0(e+2) P6:A1(e+2)
//                 P7:B0(o+2) P8:B1(o+2)  (each slot >=1 barrier-pair after last read)
// Counted waits: vmcnt(4)@P1, vmcnt(6)@P4, vmcnt(4)@P5, vmcnt(6)@P8.
template<int EPI>
__global__ __launch_bounds__(512, 2) void gemm256(
    const unsigned short* __restrict__ A,
    const unsigned short* __restrict__ Bp,
    int Kk, int Nn, int nbx,
    const float* __restrict__ bias,
    const float* __restrict__ gamma,
    const float* __restrict__ beta,
    float* __restrict__ Cf,
    unsigned short* __restrict__ Cb)
{
  __shared__ char lds[131072];
  const int t = threadIdx.x;
  const int lane = t & 63;
  const int wid = t >> 6;
  const int wr = wid >> 2;        // 0..1  (M-half)
  const int wc = wid & 3;         // 0..3  (N-quarter)

  // T1: bijective XCD swizzle (gridDim.x % 8 == 0 by construction)
  const int nw = gridDim.x;
  const int wg = (blockIdx.x & 7) * (nw >> 3) + (blockIdx.x >> 3);
  const int bx = wg % nbx;
  const int by = wg / nbx;
  const int m0 = bx << 8, n0 = by << 8;

  const int NT = Kk >> 6;         // K-tiles (BK=64), even, >=4
  const int NI = NT >> 1;         // unroll-2 iterations

  const long h64 = (long)64 * Kk, h128 = (long)128 * Kk;
  const int row0 = t >> 3;
  const int col0 = ((t & 7) * 8) ^ ((row0 & 7) << 3);   // pre-swizzled source col (elems)
  const unsigned short* gA = A  + (long)(m0 + row0) * Kk + col0;
  const unsigned short* gB = Bp + (long)(n0 + row0) * Kk + col0;

  const int fr_ = lane & 15;
  const int cb0 = ((lane >> 4) << 4) ^ ((fr_ & 7) << 4); // swizzled read col (bytes)
  const int aB = (wr << 14) + fr_ * 128;
  const int bB = 32768 + ((wc >> 1) << 14) + ((wc & 1) << 13) + fr_ * 128;

#define STG(gp_, ko_, lo_) do { \
    const unsigned short* g0_ = (gp_) + (ko_); \
    gload16(g0_, lds + (lo_) + (t << 4)); \
    gload16(g0_ + h64, lds + (lo_) + 8192 + (t << 4)); } while (0)

#define LDSA(buf_, m_, ks_) (*(const short8*)(lds + (buf_) * 65536 + aB + (m_) * 2048 + (cb0 ^ ((ks_) << 6))))
#define LDSB(buf_, n_, ks_) (*(const short8*)(lds + (buf_) * 65536 + bB + (n_) * 2048 + (cb0 ^ ((ks_) << 6))))

#define RDAF(buf_, mb_) do { \
    af[0][0] = LDSA(buf_, (mb_) + 0, 0); af[0][1] = LDSA(buf_, (mb_) + 0, 1); \
    af[1][0] = LDSA(buf_, (mb_) + 1, 0); af[1][1] = LDSA(buf_, (mb_) + 1, 1); \
    af[2][0] = LDSA(buf_, (mb_) + 2, 0); af[2][1] = LDSA(buf_, (mb_) + 2, 1); \
    af[3][0] = LDSA(buf_, (mb_) + 3, 0); af[3][1] = LDSA(buf_, (mb_) + 3, 1); } while (0)

#define RDB(buf_, nb_, dst_) do { \
    dst_[0][0] = LDSB(buf_, (nb_) + 0, 0); dst_[0][1] = LDSB(buf_, (nb_) + 0, 1); \
    dst_[1][0] = LDSB(buf_, (nb_) + 1, 0); dst_[1][1] = LDSB(buf_, (nb_) + 1, 1); } while (0)

#define QUAD(mb_, nb_, b_) do { \
    _Pragma("unroll") \
    for (int mi = 0; mi < 4; ++mi) { \
      _Pragma("unroll") \
      for (int ni = 0; ni < 2; ++ni) { \
        acc[(mb_) + mi][(nb_) + ni] = __builtin_amdgcn_mfma_f32_16x16x32_bf16(af[mi][0], b_[ni][0], acc[(mb_) + mi][(nb_) + ni], 0, 0, 0); \
        acc[(mb_) + mi][(nb_) + ni] = __builtin_amdgcn_mfma_f32_16x16x32_bf16(af[mi][1], b_[ni][1], acc[(mb_) + mi][(nb_) + ni], 0, 0, 0); \
      } } } while (0)

#define MID() do { \
    __builtin_amdgcn_sched_barrier(0); \
    __builtin_amdgcn_s_barrier(); \
    asm volatile("s_waitcnt lgkmcnt(0)" ::: "memory"); \
    __builtin_amdgcn_sched_barrier(0); \
    __builtin_amdgcn_s_setprio(1); } while (0)
#define END() do { \
    __builtin_amdgcn_s_setprio(0); \
    __builtin_amdgcn_sched_barrier(0); \
    __builtin_amdgcn_s_barrier(); \
    __builtin_amdgcn_sched_barrier(0); } while (0)

#define VM4 asm volatile("s_waitcnt vmcnt(4)" ::: "memory")
#define VM6 asm volatile("s_waitcnt vmcnt(6)" ::: "memory")
#define VM0 asm volatile("s_waitcnt vmcnt(0)" ::: "memory")

  f32x4 acc[8][4];
  #pragma unroll
  for (int i = 0; i < 8; i++)
    #pragma unroll
    for (int j = 0; j < 4; j++) acc[i][j] = (f32x4){0.f, 0.f, 0.f, 0.f};

  short8 af[4][2], b23[2][2], b0E[2][2], b0O[2][2];

  // prologue: A0(0),A1(0),B0(0),B1(0) then B0(1),B1(1); complete tile0; preload b0E(0)
  STG(gA, 0, 0);
  STG(gA + h128, 0, 16384);
  STG(gB, 0, 32768);
  STG(gB + h128, 0, 49152);
  STG(gB, 64, 98304);
  STG(gB + h128, 64, 114688);
  VM4;
  __builtin_amdgcn_s_barrier();
  __builtin_amdgcn_sched_barrier(0);
  RDB(0, 0, b0E);

#define ITERBODY(LAST_) do { \
    /* P1: q00(e) */ \
    VM4; STG(gA, ko + 64, 65536); \
    RDAF(0, 0); \
    MID(); QUAD(0, 0, b0E); END(); \
    /* P2: q01(e) */ \
    STG(gA + h128, ko + 64, 81920); \
    RDB(0, 2, b23); \
    MID(); QUAD(0, 2, b23); END(); \
    /* P3: q10(e) */ \
    if (!(LAST_)) STG(gB, ko + 128, 32768); \
    RDAF(0, 4); \
    MID(); QUAD(4, 0, b0E); END(); \
    /* P4: q11(e); pipeline-read b0(o) */ \
    if (LAST_) { VM4; } else { VM6; STG(gB + h128, ko + 128, 49152); } \
    RDB(1, 0, b0O); \
    MID(); QUAD(4, 2, b23); END(); \
    /* P5: q00(o) */ \
    if (LAST_) { VM0; } else { VM4; STG(gA, ko + 128, 0); } \
    RDAF(1, 0); \
    MID(); QUAD(0, 0, b0O); END(); \
    /* P6: q01(o) */ \
    if (!(LAST_)) STG(gA + h128, ko + 128, 16384); \
    RDB(1, 2, b23); \
    MID(); QUAD(0, 2, b23); END(); \
    /* P7: q10(o) */ \
    if (!(LAST_)) STG(gB, ko + 192, 98304); \
    RDAF(1, 4); \
    MID(); QUAD(4, 0, b0O); END(); \
    /* P8: q11(o); pipeline-read b0E(e+2) */ \
    if (!(LAST_)) { VM6; STG(gB + h128, ko + 192, 114688); RDB(0, 0, b0E); } \
    MID(); QUAD(4, 2, b23); END(); \
  } while (0)

  long ko = 0;
  for (int i = 0; i < NI - 1; ++i, ko += 128) {
    ITERBODY(0);
  }
  ITERBODY(1);

  // ---- epilogue
  const int l4 = lane >> 4;
  #pragma unroll
  for (int m = 0; m < 8; ++m) {
    const int r0 = m0 + wr * 128 + m * 16 + l4 * 4;
    #pragma unroll
    for (int n = 0; n < 4; ++n) {
      const int cn = n0 + wc * 64 + n * 16 + fr_;
      if constexpr (EPI == 1) {
        float s1 = 0.f, s2 = 0.f;
        #pragma unroll
        for (int j = 0; j < 4; j++) { float v = acc[m][n][j]; s1 += v; s2 += v * v; }
        s1 += __shfl_xor(s1, 16); s2 += __shfl_xor(s2, 16);
        s1 += __shfl_xor(s1, 32); s2 += __shfl_xor(s2, 32);
        const float mean = s1 * 0.0625f;
        const float var  = s2 * 0.0625f - mean * mean;
        const float sc = rsqrtf(var + EPS) * gamma[cn];
        const float sh = beta[cn] - mean * sc;
        #pragma unroll
        for (int j = 0; j < 4; j++) {
          float v = fmaxf(acc[m][n][j] * sc + sh, 0.f);
          Cb[(long)(r0 + j) * Nn + cn] = f2b(v);
        }
      } else {
        const float bb = bias[cn];
        #pragma unroll
        for (int j = 0; j < 4; j++)
          Cf[(long)(r0 + j) * Nn + cn] = acc[m][n][j] + bb;
      }
    }
  }
#undef STG
#undef LDSA
#undef LDSB
#undef RDAF
#undef RDB
#undef QUAD
#undef MID
#undef END
#undef VM4
#undef VM6
#undef VM0
#undef ITERBODY
}

extern "C" void kernel_launch(void* const* d_in, const int* in_sizes, int n_in,
                              void* d_out, int out_size, void* d_ws, size_t ws_size,
                              hipStream_t stream) {
  const float* X     = (const float*)d_in[0];
  const float* W_att = (const float*)d_in[1];
  const float* b_att = (const float*)d_in[2];
  const float* W1    = (const float*)d_in[3];
  // d_in[4] = b1: cancels exactly in BN (mean-subtracted) -> unused
  const float* gamma = (const float*)d_in[5];
  const float* beta  = (const float*)d_in[6];
  const float* W2    = (const float*)d_in[7];
  const float* b2    = (const float*)d_in[8];
  float* out = (float*)d_out;

  char* ws = (char*)d_ws;
  unsigned short* Wab = (unsigned short*)(ws + 0);            //  8 MB
  unsigned short* W1b = (unsigned short*)(ws + 8388608);      //  8 MB
  unsigned short* W2b = (unsigned short*)(ws + 16777216);     //  8 MB
  float*          Pat = (float*)        (ws + 25165824);      //  8 MB (P0+P1 split-K partials)
  unsigned short* Xg  = (unsigned short*)(ws + 33554432);     // 32 MB
  unsigned short* Hr  = (unsigned short*)(ws + 67108864);     // 32 MB
  // Mb aliases the Hr region: consumed (gemm_att_sk) strictly before Hr is written.
  unsigned short* Mb  = (unsigned short*)(ws + 67108864);     //  2 MB (alias)

  hipLaunchKernelGGL(cast3_kernel, dim3(12288), dim3(256), 0, stream,
                     W_att, W1, W2, Wab, W1b, W2b);
  hipLaunchKernelGGL(mean_cast_kernel, dim3(1024), dim3(256), 0, stream, X, Mb);
  hipLaunchKernelGGL(gemm_att_sk, dim3(4, 16, 2), dim3(256), 0, stream,
                     Mb, Wab, Pat);
  hipLaunchKernelGGL(gate_kernel, dim3(16384), dim3(256), 0, stream,
                     X, Pat, Pat + 512L * 2048, b_att, Xg);
  // grid = (M/256)*(N/256) = 32*8 = 256, %8==0 -> bijective XCD swizzle
  hipLaunchKernelGGL((gemm256<1>), dim3(256), dim3(512), 0, stream,
                     Xg, W1b, Cdim, Cdim, 32, nullptr, gamma, beta, nullptr, Hr);
  hipLaunchKernelGGL((gemm256<2>), dim3(256), dim3(512), 0, stream,
                     Hr, W2b, Cdim, Cdim, 32, b2, nullptr, nullptr, out, nullptr);
}

// Round 4
// 188.427 us; speedup vs baseline: 1.5812x; 1.0236x over previous
//
#include <hip/hip_runtime.h>
#include <hip/hip_bf16.h>

typedef __attribute__((ext_vector_type(8))) short short8;
typedef __attribute__((ext_vector_type(4))) float f32x4;

static constexpr int Cdim = 2048;
static constexpr int NFRM = 512;        // B*T
static constexpr int Pdim = 16;
static constexpr int MROWS = NFRM * Pdim;   // 8192
static constexpr float EPS = 1e-5f;

// round-to-nearest-even fp32 -> bf16 bits
__device__ __forceinline__ unsigned short f2b(float x) {
  union { float f; unsigned u; } v; v.f = x;
  unsigned r = v.u + 0x7fffu + ((v.u >> 16) & 1u);
  return (unsigned short)(r >> 16);
}

__device__ __forceinline__ void gload16(const void* g, void* l) {
  __builtin_amdgcn_global_load_lds(
      (const __attribute__((address_space(1))) unsigned int*)g,
      (__attribute__((address_space(3))) unsigned int*)l, 16, 0, 0);
}

// ---------------- small prep kernels ----------------

__global__ __launch_bounds__(256) void cast3_kernel(
    const float* __restrict__ s0, const float* __restrict__ s1, const float* __restrict__ s2,
    unsigned short* __restrict__ d0, unsigned short* __restrict__ d1, unsigned short* __restrict__ d2)
{
  long i = (long)blockIdx.x * 256 + threadIdx.x;
  const float* s; unsigned short* d; long off;
  if (i < 1048576)      { s = s0; d = d0; off = i; }
  else if (i < 2097152) { s = s1; d = d1; off = i - 1048576; }
  else                  { s = s2; d = d2; off = i - 2097152; }
  float4 v = reinterpret_cast<const float4*>(s)[off];
  union { unsigned short u[4]; unsigned long long q; } o;
  o.u[0] = f2b(v.x); o.u[1] = f2b(v.y); o.u[2] = f2b(v.z); o.u[3] = f2b(v.w);
  *reinterpret_cast<unsigned long long*>(d + off * 4) = o.q;
}

__global__ __launch_bounds__(256) void mean_cast_kernel(
    const float* __restrict__ X, unsigned short* __restrict__ Mb)
{
  int idx = blockIdx.x * 256 + threadIdx.x;
  int n  = idx >> 9;
  int c4 = idx & 511;
  const float4* xp = reinterpret_cast<const float4*>(X) + (long)n * (Pdim * 512) + c4;
  float4 s = {0.f, 0.f, 0.f, 0.f};
  #pragma unroll
  for (int p = 0; p < Pdim; ++p) {
    float4 v = xp[(long)p * 512];
    s.x += v.x; s.y += v.y; s.z += v.z; s.w += v.w;
  }
  const float r = 1.f / 16.f;
  union { unsigned short u[4]; unsigned long long q; } o;
  o.u[0] = f2b(s.x * r); o.u[1] = f2b(s.y * r); o.u[2] = f2b(s.z * r); o.u[3] = f2b(s.w * r);
  *reinterpret_cast<unsigned long long*>(Mb + (long)idx * 4) = o.q;
}

// attn partials -> sigmoid gate fused here: a = sigmoid(P0+P1+b_att); Xg = bf16(X*a)
__global__ __launch_bounds__(256) void gate_kernel(
    const float* __restrict__ X, const float* __restrict__ P0, const float* __restrict__ P1,
    const float* __restrict__ b_att, unsigned short* __restrict__ Xg)
{
  long idx = (long)blockIdx.x * 256 + threadIdx.x;
  int c4 = (int)(idx & 511);
  long np = idx >> 9;
  long n  = np >> 4;
  float4 x  = reinterpret_cast<const float4*>(X)[idx];
  float4 p0 = reinterpret_cast<const float4*>(P0)[n * 512 + c4];
  float4 p1 = reinterpret_cast<const float4*>(P1)[n * 512 + c4];
  float4 bb = reinterpret_cast<const float4*>(b_att)[c4];
  float4 a;
  a.x = 1.f / (1.f + __expf(-(p0.x + p1.x + bb.x)));
  a.y = 1.f / (1.f + __expf(-(p0.y + p1.y + bb.y)));
  a.z = 1.f / (1.f + __expf(-(p0.z + p1.z + bb.z)));
  a.w = 1.f / (1.f + __expf(-(p0.w + p1.w + bb.w)));
  union { unsigned short u[4]; unsigned long long q; } o;
  o.u[0] = f2b(x.x * a.x); o.u[1] = f2b(x.y * a.y);
  o.u[2] = f2b(x.z * a.z); o.u[3] = f2b(x.w * a.w);
  *reinterpret_cast<unsigned long long*>(Xg + idx * 4) = o.q;
}

// ---------------- small attn GEMM, split-K=2, raw partial output ----------------
__global__ __launch_bounds__(256) void gemm_att_sk(
    const unsigned short* __restrict__ A,
    const unsigned short* __restrict__ B,
    float* __restrict__ P)
{
  constexpr int N = 2048, K = 2048, KH = 1024;
  __shared__ unsigned short As[128 * 32];
  __shared__ unsigned short Bs[128 * 32];
  const int t = threadIdx.x;
  const int lane = t & 63;
  const int wid = t >> 6;
  const int wr = wid >> 1, wc = wid & 1;
  const int m0 = blockIdx.x * 128, n0 = blockIdx.y * 128;
  const int k0 = blockIdx.z * KH;
  float* out = P + (long)blockIdx.z * (512L * 2048);

  f32x4 acc[4][4];
  #pragma unroll
  for (int i = 0; i < 4; i++)
    #pragma unroll
    for (int j = 0; j < 4; j++) acc[i][j] = (f32x4){0.f, 0.f, 0.f, 0.f};

  const int srow = t >> 2;
  const int scol = (t & 3) * 8;
  const long aoff0 = (long)(m0 + srow) * K + scol;
  const long aoff1 = (long)(m0 + 64 + srow) * K + scol;
  const long boff0 = (long)(n0 + srow) * K + scol;
  const long boff1 = (long)(n0 + 64 + srow) * K + scol;
  char* AsB = (char*)As;
  char* BsB = (char*)Bs;

  const int fr = lane & 15;
  const int fk = (lane >> 4) * 8;

  for (int kt = k0; kt < k0 + KH; kt += 32) {
    __syncthreads();
    gload16(A + aoff0 + kt, AsB + t * 16);
    gload16(A + aoff1 + kt, AsB + 4096 + t * 16);
    gload16(B + boff0 + kt, BsB + t * 16);
    gload16(B + boff1 + kt, BsB + 4096 + t * 16);
    __syncthreads();
    short8 af[4], bfr[4];
    #pragma unroll
    for (int m = 0; m < 4; m++)
      af[m] = *reinterpret_cast<const short8*>(&As[(wr * 64 + m * 16 + fr) * 32 + fk]);
    #pragma unroll
    for (int n = 0; n < 4; n++)
      bfr[n] = *reinterpret_cast<const short8*>(&Bs[(wc * 64 + n * 16 + fr) * 32 + fk]);
    #pragma unroll
    for (int m = 0; m < 4; m++)
      #pragma unroll
      for (int n = 0; n < 4; n++)
        acc[m][n] = __builtin_amdgcn_mfma_f32_16x16x32_bf16(af[m], bfr[n], acc[m][n], 0, 0, 0);
  }

  const int l4 = lane >> 4;
  #pragma unroll
  for (int m = 0; m < 4; m++) {
    const int r0 = m0 + wr * 64 + m * 16 + l4 * 4;
    #pragma unroll
    for (int n = 0; n < 4; n++) {
      const int cn = n0 + wc * 64 + n * 16 + fr;
      #pragma unroll
      for (int j = 0; j < 4; j++)
        out[(long)(r0 + j) * N + cn] = acc[m][n][j];
    }
  }
}

// ---------------- 256^2 single-barrier 8-phase GEMM (T1+T2+T3+T4+T5) ----------------
// C[M,N] = A[M,K] @ B[N,K]^T, bf16 in / fp32 acc.
//   EPI=1: Cb = bf16(relu(BN_P16(acc)*gamma+beta))
//   EPI=2: Cf = acc + bias
// ONE barrier per phase: [vmcnt?][stage][reads] -> s_barrier -> lgkmcnt(0) ->
// setprio(1) -> 16 MFMA -> setprio(0). Waves desync within a phase window ->
// next phase's ds_reads overlap siblings' MFMA.
// Ledger (race-free, verified):
//  stages: P1:A0(o) P2:A1(o) P3:B0(e+2) P4:B1(e+2) P5:A0(e+2) P6:A1(e+2)
//          P7:B0(o+2) P8:B1(o+2)
//  vmcnt:  P3:4 (confirms B(o) for P4 pre-read)   P4:2 (confirms A(o) for P5)
//          P7:4 (confirms B(e+2) for P8 pre-read) P8:2 (confirms A(e+2) for P1')
//  WAR: every stage-issue follows the barrier after its slot's last read.
//  Outstanding-load invariant per phase start: 4,6,8,{4+1},{2+1},... closes.
template<int EPI>
__global__ __launch_bounds__(512, 2) void gemm256(
    const unsigned short* __restrict__ A,
    const unsigned short* __restrict__ Bp,
    int Kk, int Nn, int nbx,
    const float* __restrict__ bias,
    const float* __restrict__ gamma,
    const float* __restrict__ beta,
    float* __restrict__ Cf,
    unsigned short* __restrict__ Cb)
{
  __shared__ char lds[131072];
  const int t = threadIdx.x;
  const int lane = t & 63;
  const int wid = t >> 6;
  const int wr = wid >> 2;        // 0..1  (M-half)
  const int wc = wid & 3;         // 0..3  (N-quarter)

  // T1: bijective XCD swizzle (gridDim.x % 8 == 0 by construction)
  const int nw = gridDim.x;
  const int wg = (blockIdx.x & 7) * (nw >> 3) + (blockIdx.x >> 3);
  const int bx = wg % nbx;
  const int by = wg / nbx;
  const int m0 = bx << 8, n0 = by << 8;

  const int NT = Kk >> 6;         // K-tiles (BK=64), even, >=4
  const int NI = NT >> 1;         // unroll-2 iterations

  const long h64 = (long)64 * Kk, h128 = (long)128 * Kk;
  const int row0 = t >> 3;
  const int col0 = ((t & 7) * 8) ^ ((row0 & 7) << 3);   // pre-swizzled source col (elems)
  const unsigned short* gA = A  + (long)(m0 + row0) * Kk + col0;
  const unsigned short* gB = Bp + (long)(n0 + row0) * Kk + col0;

  const int fr_ = lane & 15;
  const int cb0 = ((lane >> 4) << 4) ^ ((fr_ & 7) << 4); // swizzled read col (bytes)
  const int aB = (wr << 14) + fr_ * 128;
  const int bB = 32768 + ((wc >> 1) << 14) + ((wc & 1) << 13) + fr_ * 128;

#define STG(gp_, ko_, lo_) do { \
    const unsigned short* g0_ = (gp_) + (ko_); \
    gload16(g0_, lds + (lo_) + (t << 4)); \
    gload16(g0_ + h64, lds + (lo_) + 8192 + (t << 4)); } while (0)

#define LDSA(buf_, m_, ks_) (*(const short8*)(lds + (buf_) * 65536 + aB + (m_) * 2048 + (cb0 ^ ((ks_) << 6))))
#define LDSB(buf_, n_, ks_) (*(const short8*)(lds + (buf_) * 65536 + bB + (n_) * 2048 + (cb0 ^ ((ks_) << 6))))

#define RDAF(buf_, mb_) do { \
    af[0][0] = LDSA(buf_, (mb_) + 0, 0); af[0][1] = LDSA(buf_, (mb_) + 0, 1); \
    af[1][0] = LDSA(buf_, (mb_) + 1, 0); af[1][1] = LDSA(buf_, (mb_) + 1, 1); \
    af[2][0] = LDSA(buf_, (mb_) + 2, 0); af[2][1] = LDSA(buf_, (mb_) + 2, 1); \
    af[3][0] = LDSA(buf_, (mb_) + 3, 0); af[3][1] = LDSA(buf_, (mb_) + 3, 1); } while (0)

#define RDB(buf_, nb_, dst_) do { \
    dst_[0][0] = LDSB(buf_, (nb_) + 0, 0); dst_[0][1] = LDSB(buf_, (nb_) + 0, 1); \
    dst_[1][0] = LDSB(buf_, (nb_) + 1, 0); dst_[1][1] = LDSB(buf_, (nb_) + 1, 1); } while (0)

#define QUAD(mb_, nb_, b_) do { \
    _Pragma("unroll") \
    for (int mi = 0; mi < 4; ++mi) { \
      _Pragma("unroll") \
      for (int ni = 0; ni < 2; ++ni) { \
        acc[(mb_) + mi][(nb_) + ni] = __builtin_amdgcn_mfma_f32_16x16x32_bf16(af[mi][0], b_[ni][0], acc[(mb_) + mi][(nb_) + ni], 0, 0, 0); \
        acc[(mb_) + mi][(nb_) + ni] = __builtin_amdgcn_mfma_f32_16x16x32_bf16(af[mi][1], b_[ni][1], acc[(mb_) + mi][(nb_) + ni], 0, 0, 0); \
      } } } while (0)

// single barrier per phase: rendezvous, then drain own ds_reads, pin MFMA after.
#define BARX() do { \
    __builtin_amdgcn_sched_barrier(0); \
    __builtin_amdgcn_s_barrier(); \
    asm volatile("s_waitcnt lgkmcnt(0)" ::: "memory"); \
    __builtin_amdgcn_sched_barrier(0); } while (0)

#define PRIO1() __builtin_amdgcn_s_setprio(1)
#define PRIO0() __builtin_amdgcn_s_setprio(0)
#define VMC(n_) asm volatile("s_waitcnt vmcnt(" #n_ ")" ::: "memory")

  f32x4 acc[8][4];
  #pragma unroll
  for (int i = 0; i < 8; i++)
    #pragma unroll
    for (int j = 0; j < 4; j++) acc[i][j] = (f32x4){0.f, 0.f, 0.f, 0.f};

  short8 af[4][2], b23[2][2], b0E[2][2], b0O[2][2];

  // prologue: A0(0),A1(0),B0(0),B1(0),B0(1),B1(1); confirm first 4; pre-read b0E(0).
  // Leaves outstanding = {B0(1),B1(1)} = 4 loads = steady-state P1-entry invariant.
  STG(gA, 0, 0);
  STG(gA + h128, 0, 16384);
  STG(gB, 0, 32768);
  STG(gB + h128, 0, 49152);
  STG(gB, 64, 98304);
  STG(gB + h128, 64, 114688);
  VMC(4);
  __builtin_amdgcn_s_barrier();
  __builtin_amdgcn_sched_barrier(0);
  RDB(0, 0, b0E);

#define ITERBODY(LAST_) do { \
    /* P1: q00(e); stage A0(o) */ \
    STG(gA, ko + 64, 65536); \
    RDAF(0, 0); \
    BARX(); PRIO1(); QUAD(0, 0, b0E); PRIO0(); \
    /* P2: q01(e); stage A1(o) */ \
    STG(gA + h128, ko + 64, 81920); \
    RDB(0, 2, b23); \
    BARX(); PRIO1(); QUAD(0, 2, b23); PRIO0(); \
    /* P3: q10(e); vmcnt confirms B(o); stage B0(e+2) */ \
    VMC(4); \
    if (!(LAST_)) STG(gB, ko + 128, 32768); \
    RDAF(0, 4); \
    BARX(); PRIO1(); QUAD(4, 0, b0E); PRIO0(); \
    /* P4: q11(e); vmcnt confirms A(o); stage B1(e+2); pre-read b0(o) */ \
    if (LAST_) { VMC(0); } else { VMC(2); STG(gB + h128, ko + 128, 49152); } \
    RDB(1, 0, b0O); \
    BARX(); PRIO1(); QUAD(4, 2, b23); PRIO0(); \
    /* P5: q00(o); stage A0(e+2) */ \
    if (!(LAST_)) STG(gA, ko + 128, 0); \
    RDAF(1, 0); \
    BARX(); PRIO1(); QUAD(0, 0, b0O); PRIO0(); \
    /* P6: q01(o); stage A1(e+2) */ \
    if (!(LAST_)) STG(gA + h128, ko + 128, 16384); \
    RDB(1, 2, b23); \
    BARX(); PRIO1(); QUAD(0, 2, b23); PRIO0(); \
    /* P7: q10(o); vmcnt confirms B(e+2); stage B0(o+2) */ \
    if (!(LAST_)) { VMC(4); STG(gB, ko + 192, 98304); } \
    RDAF(1, 4); \
    BARX(); PRIO1(); QUAD(4, 0, b0O); PRIO0(); \
    /* P8: q11(o); vmcnt confirms A(e+2); stage B1(o+2); pre-read b0E(e+2) */ \
    if (!(LAST_)) { VMC(2); STG(gB + h128, ko + 192, 114688); RDB(0, 0, b0E); } \
    BARX(); PRIO1(); QUAD(4, 2, b23); PRIO0(); \
  } while (0)

  long ko = 0;
  for (int i = 0; i < NI - 1; ++i, ko += 128) {
    ITERBODY(0);
  }
  ITERBODY(1);

  // ---- epilogue (acc only; no LDS use, no barrier needed)
  const int l4 = lane >> 4;
  #pragma unroll
  for (int m = 0; m < 8; ++m) {
    const int r0 = m0 + wr * 128 + m * 16 + l4 * 4;
    #pragma unroll
    for (int n = 0; n < 4; ++n) {
      const int cn = n0 + wc * 64 + n * 16 + fr_;
      if constexpr (EPI == 1) {
        float s1 = 0.f, s2 = 0.f;
        #pragma unroll
        for (int j = 0; j < 4; j++) { float v = acc[m][n][j]; s1 += v; s2 += v * v; }
        s1 += __shfl_xor(s1, 16); s2 += __shfl_xor(s2, 16);
        s1 += __shfl_xor(s1, 32); s2 += __shfl_xor(s2, 32);
        const float mean = s1 * 0.0625f;
        const float var  = s2 * 0.0625f - mean * mean;
        const float sc = rsqrtf(var + EPS) * gamma[cn];
        const float sh = beta[cn] - mean * sc;
        #pragma unroll
        for (int j = 0; j < 4; j++) {
          float v = fmaxf(acc[m][n][j] * sc + sh, 0.f);
          Cb[(long)(r0 + j) * Nn + cn] = f2b(v);
        }
      } else {
        const float bb = bias[cn];
        #pragma unroll
        for (int j = 0; j < 4; j++)
          Cf[(long)(r0 + j) * Nn + cn] = acc[m][n][j] + bb;
      }
    }
  }
#undef STG
#undef LDSA
#undef LDSB
#undef RDAF
#undef RDB
#undef QUAD
#undef BARX
#undef PRIO1
#undef PRIO0
#undef VMC
#undef ITERBODY
}

extern "C" void kernel_launch(void* const* d_in, const int* in_sizes, int n_in,
                              void* d_out, int out_size, void* d_ws, size_t ws_size,
                              hipStream_t stream) {
  const float* X     = (const float*)d_in[0];
  const float* W_att = (const float*)d_in[1];
  const float* b_att = (const float*)d_in[2];
  const float* W1    = (const float*)d_in[3];
  // d_in[4] = b1: cancels exactly in BN (mean-subtracted) -> unused
  const float* gamma = (const float*)d_in[5];
  const float* beta  = (const float*)d_in[6];
  const float* W2    = (const float*)d_in[7];
  const float* b2    = (const float*)d_in[8];
  float* out = (float*)d_out;

  char* ws = (char*)d_ws;
  unsigned short* Wab = (unsigned short*)(ws + 0);            //  8 MB
  unsigned short* W1b = (unsigned short*)(ws + 8388608);      //  8 MB
  unsigned short* W2b = (unsigned short*)(ws + 16777216);     //  8 MB
  float*          Pat = (float*)        (ws + 25165824);      //  8 MB (P0+P1 split-K partials)
  unsigned short* Xg  = (unsigned short*)(ws + 33554432);     // 32 MB
  unsigned short* Hr  = (unsigned short*)(ws + 67108864);     // 32 MB
  // Mb aliases the Hr region: consumed (gemm_att_sk) strictly before Hr is written.
  unsigned short* Mb  = (unsigned short*)(ws + 67108864);     //  2 MB (alias)

  hipLaunchKernelGGL(cast3_kernel, dim3(12288), dim3(256), 0, stream,
                     W_att, W1, W2, Wab, W1b, W2b);
  hipLaunchKernelGGL(mean_cast_kernel, dim3(1024), dim3(256), 0, stream, X, Mb);
  hipLaunchKernelGGL(gemm_att_sk, dim3(4, 16, 2), dim3(256), 0, stream,
                     Mb, Wab, Pat);
  hipLaunchKernelGGL(gate_kernel, dim3(16384), dim3(256), 0, stream,
                     X, Pat, Pat + 512L * 2048, b_att, Xg);
  // grid = (M/256)*(N/256) = 32*8 = 256, %8==0 -> bijective XCD swizzle
  hipLaunchKernelGGL((gemm256<1>), dim3(256), dim3(512), 0, stream,
                     Xg, W1b, Cdim, Cdim, 32, nullptr, gamma, beta, nullptr, Hr);
  hipLaunchKernelGGL((gemm256<2>), dim3(256), dim3(512), 0, stream,
                     Hr, W2b, Cdim, Cdim, 32, b2, nullptr, nullptr, out, nullptr);
}